// Round 3
// baseline (595.964 us; speedup 1.0000x reference)
//
#include <hip/hip_runtime.h>

#define N_NODES 50000
#define D_FEAT 64
#define N_NNZ 800000
#define N_ENT 65536   // 2 * 32768 edge endpoints

typedef unsigned int uint32;
typedef unsigned short ushort16;

// Plane strides for plane-major [3][N][64] bf16 tables
#define PLANE_U4 ((size_t)N_NODES * 8)    // in uint4 (16B) units
#define PLANE_US ((size_t)N_NODES * 64)   // in ushort units

// ---- bf16 helpers ---------------------------------------------------------
__device__ __forceinline__ uint32 rne1(float a) {
    uint32 u = __float_as_uint(a);
    return (u + 0x7FFFu + ((u >> 16) & 1u)) >> 16;
}
__device__ __forceinline__ uint32 rne2(float a, float b) {   // pack [a:lo, b:hi]
    return rne1(a) | (rne1(b) << 16);
}
__device__ __forceinline__ float bf_lo(uint32 u) { return __uint_as_float(u << 16); }
__device__ __forceinline__ float bf_hi(uint32 u) { return __uint_as_float(u & 0xFFFF0000u); }
__device__ __forceinline__ void unpack8(const uint4 v, float* f) {
    f[0] = bf_lo(v.x); f[1] = bf_hi(v.x);
    f[2] = bf_lo(v.y); f[3] = bf_hi(v.y);
    f[4] = bf_lo(v.z); f[5] = bf_hi(v.z);
    f[6] = bf_lo(v.w); f[7] = bf_hi(v.w);
}
__device__ __forceinline__ float bf1(ushort16 u) { return __uint_as_float(((uint32)u) << 16); }

// ---------------------------------------------------------------------------
// 1a) CSR row pointers (binary search over sorted adj_row) + per-node scalars
//     scal[n] = {1/deg, rsqrt(deg), sqrt(deg), 0}. Also zeros flag[] and
//     the two degree histograms (used by later dispatches on this stream).
// ---------------------------------------------------------------------------
__global__ void build_rowptr_scal(const int* __restrict__ adj_row,
                                  const float* __restrict__ deg,
                                  int* __restrict__ row_ptr,
                                  float4* __restrict__ scal,
                                  int* __restrict__ flag,
                                  int* __restrict__ hist1,
                                  int* __restrict__ hist2,
                                  int nnz, int n) {
    int r = blockIdx.x * blockDim.x + threadIdx.x;
    if (r > n) return;
    int lo = 0, hi = nnz;           // first idx with adj_row[idx] >= r
    while (lo < hi) {
        int mid = (lo + hi) >> 1;
        if (adj_row[mid] < r) lo = mid + 1; else hi = mid;
    }
    row_ptr[r] = lo;
    if (r < n) {
        float d  = deg[r];
        float sq = sqrtf(d);
        scal[r] = make_float4(1.0f / d, 1.0f / sq, sq, 0.0f);
        flag[r] = 0;
    }
    if (r < 64) { hist1[r] = 0; hist2[r] = 0; }
}

// 1b) x (fp32) -> xh (bf16 pairs); also flags edge-endpoint nodes.
__global__ __launch_bounds__(256) void pack_x(const float2* __restrict__ x2,
                                              uint32* __restrict__ xh,
                                              const int* __restrict__ edge,
                                              int* __restrict__ flag, int npair) {
    int i = blockIdx.x * blockDim.x + threadIdx.x;
    if (i >= npair) return;
    float2 v = x2[i];
    xh[i] = rne2(v.x, v.y);
    if (i < N_ENT) flag[edge[i]] = 1;        // benign write race
}

// 1c) degree histogram: all rows -> hist1, edge-needed rows -> hist2
__global__ __launch_bounds__(256) void hist_kernel(
    const int* __restrict__ row_ptr, const int* __restrict__ flag,
    int* __restrict__ hist1, int* __restrict__ hist2, int n) {
    int r = blockIdx.x * blockDim.x + threadIdx.x;
    if (r >= n) return;
    int b = min(row_ptr[r + 1] - row_ptr[r], 63);
    atomicAdd(&hist1[b], 1);
    if (flag[r]) atomicAdd(&hist2[b], 1);
}

// 1d) descending-degree exclusive prefix -> bucket cursors; n_needed count.
__global__ void prefix_kernel(const int* __restrict__ hist1,
                              const int* __restrict__ hist2,
                              int* __restrict__ cur1, int* __restrict__ cur2,
                              int* __restrict__ n_needed) {
    if (threadIdx.x == 0) {
        int acc = 0;
        for (int b = 63; b >= 0; --b) { cur1[b] = acc; acc += hist1[b]; }
        int acc2 = 0;
        for (int b = 63; b >= 0; --b) { cur2[b] = acc2; acc2 += hist2[b]; }
        *n_needed = acc2;
    }
}

// 1e) scatter rows into degree-sorted perms (equal-degree waves => no
//     divergence waste in spmm; descending => long rows dispatch first).
__global__ __launch_bounds__(256) void scatter_kernel(
    const int* __restrict__ row_ptr, const int* __restrict__ flag,
    int* __restrict__ cur1, int* __restrict__ cur2,
    int* __restrict__ perm1, int* __restrict__ perm2, int n) {
    int r = blockIdx.x * blockDim.x + threadIdx.x;
    if (r >= n) return;
    int b = min(row_ptr[r + 1] - row_ptr[r], 63);
    int p = atomicAdd(&cur1[b], 1);
    perm1[p] = r;
    if (flag[r]) { int q = atomicAdd(&cur2[b], 1); perm2[q] = r; }
}

// ---------------------------------------------------------------------------
// 2) y1 = degrev * spmm(x3). Wave = 8 rows via perm1 (equal degree), octet
//    walks its row serially (2-way MLP). Output plane-major [3][N][64] bf16.
// ---------------------------------------------------------------------------
__global__ __launch_bounds__(256) void spmm1_kernel(
    const uint4* __restrict__ xh, const float4* __restrict__ scal,
    const int* __restrict__ adj_col, const int* __restrict__ row_ptr,
    const int* __restrict__ perm1,
    uint4* __restrict__ y1h, int n) {
    int t    = threadIdx.x & 63;
    int f    = t & 7;                                  // feature block
    int idx  = (blockIdx.x * 4 + (threadIdx.x >> 6)) * 8 + (t >> 3);
    if (idx >= n) return;
    int r = perm1[idx];

    int s = row_ptr[r], e = row_ptr[r + 1];
    int cnt = e - s;
    float a0[8], a1[8], a2[8];
#pragma unroll
    for (int j = 0; j < 8; ++j) { a0[j] = 0.f; a1[j] = 0.f; a2[j] = 0.f; }

    int i = 0;
    for (; i + 2 <= cnt; i += 2) {
        int c0 = adj_col[s + i];
        int c1 = adj_col[s + i + 1];
        uint4 xv0 = xh[(size_t)c0 * 8 + f];
        uint4 xv1 = xh[(size_t)c1 * 8 + f];
        float4 sc0 = scal[c0];
        float4 sc1 = scal[c1];
        float xf0[8], xf1[8];
        unpack8(xv0, xf0); unpack8(xv1, xf1);
#pragma unroll
        for (int j = 0; j < 8; ++j) {
            a0[j] += xf0[j];
            a1[j] += xf0[j] * sc0.y;
            a2[j] += xf0[j] * sc0.z;
            a0[j] += xf1[j];
            a1[j] += xf1[j] * sc1.y;
            a2[j] += xf1[j] * sc1.z;
        }
    }
    if (i < cnt) {
        int c = adj_col[s + i];
        uint4 xv = xh[(size_t)c * 8 + f];
        float4 sc = scal[c];
        float xf[8]; unpack8(xv, xf);
#pragma unroll
        for (int j = 0; j < 8; ++j) {
            a0[j] += xf[j];
            a1[j] += xf[j] * sc.y;
            a2[j] += xf[j] * sc.z;
        }
    }

    float dr = scal[r].x;
    size_t base = (size_t)r * 8 + f;
    y1h[base]               = make_uint4(rne2(a0[0]*dr, a0[1]*dr), rne2(a0[2]*dr, a0[3]*dr),
                                         rne2(a0[4]*dr, a0[5]*dr), rne2(a0[6]*dr, a0[7]*dr));
    y1h[base + PLANE_U4]    = make_uint4(rne2(a1[0]*dr, a1[1]*dr), rne2(a1[2]*dr, a1[3]*dr),
                                         rne2(a1[4]*dr, a1[5]*dr), rne2(a1[6]*dr, a1[7]*dr));
    y1h[base + 2*PLANE_U4]  = make_uint4(rne2(a2[0]*dr, a2[1]*dr), rne2(a2[2]*dr, a2[3]*dr),
                                         rne2(a2[4]*dr, a2[5]*dr), rne2(a2[6]*dr, a2[7]*dr));
}

// ---------------------------------------------------------------------------
// 3) y2 = degrev * spmm(y1) - x3, one group per pass (blockIdx.y), rows via
//    perm2 (edge-needed only, ~73% of N, equal-degree waves). Surplus blocks
//    early-exit on device-side count (no host sync).
// ---------------------------------------------------------------------------
__global__ __launch_bounds__(256) void spmm2_kernel(
    const float4* __restrict__ x4, const float4* __restrict__ scal,
    const int* __restrict__ adj_col, const int* __restrict__ row_ptr,
    const int* __restrict__ perm2, const int* __restrict__ n_needed,
    const uint4* __restrict__ y1h, uint4* __restrict__ y2h) {
    int t = threadIdx.x & 63;
    int f = t & 7;
    int idx = (blockIdx.x * 4 + (threadIdx.x >> 6)) * 8 + (t >> 3);
    int g = blockIdx.y;
    if (idx >= *n_needed) return;
    int r = perm2[idx];
    const uint4* yp = y1h + (size_t)g * PLANE_U4;

    int s = row_ptr[r], e = row_ptr[r + 1];
    int cnt = e - s;
    float a[8];
#pragma unroll
    for (int j = 0; j < 8; ++j) a[j] = 0.f;

    int i = 0;
    for (; i + 4 <= cnt; i += 4) {                 // 4 gathers in flight/octet
        int c0 = adj_col[s + i];
        int c1 = adj_col[s + i + 1];
        int c2 = adj_col[s + i + 2];
        int c3 = adj_col[s + i + 3];
        uint4 b0 = yp[(size_t)c0 * 8 + f];
        uint4 b1 = yp[(size_t)c1 * 8 + f];
        uint4 b2 = yp[(size_t)c2 * 8 + f];
        uint4 b3 = yp[(size_t)c3 * 8 + f];
        float f0[8], f1[8], f2[8], f3[8];
        unpack8(b0, f0); unpack8(b1, f1); unpack8(b2, f2); unpack8(b3, f3);
#pragma unroll
        for (int j = 0; j < 8; ++j)
            a[j] += (f0[j] + f1[j]) + (f2[j] + f3[j]);
    }
    for (; i < cnt; ++i) {
        int c = adj_col[s + i];
        uint4 b = yp[(size_t)c * 8 + f];
        float fv[8]; unpack8(b, fv);
#pragma unroll
        for (int j = 0; j < 8; ++j) a[j] += fv[j];
    }

    float4 sc = scal[r];                       // {1/d, rsqrt, sqrt, 0}
    float w = (g == 0) ? 1.0f : ((g == 1) ? sc.y : sc.z);
    float4 xa = x4[(size_t)r * 16 + f * 2];
    float4 xb = x4[(size_t)r * 16 + f * 2 + 1];
    float xr[8] = {xa.x, xa.y, xa.z, xa.w, xb.x, xb.y, xb.z, xb.w};
    float v[8];
#pragma unroll
    for (int j = 0; j < 8; ++j) v[j] = sc.x * a[j] - xr[j] * w;

    uint4* yr = y2h + (size_t)g * PLANE_U4 + (size_t)r * 8 + f;
    yr[0] = make_uint4(rne2(v[0], v[1]), rne2(v[2], v[3]),
                       rne2(v[4], v[5]), rne2(v[6], v[7]));
}

// ---------------------------------------------------------------------------
// 4) Output gather + [64,9] transpose through LDS; float4 store path.
//    out[ent, d, g]: g 0..2 = x*{1,rsqrt,sqrt}, g 3..5 = y1, g 6..8 = y2.
//    y1/y2 plane-major: plane stride N*64 ushorts.
// ---------------------------------------------------------------------------
__global__ __launch_bounds__(256) void gather_kernel(
    const float* __restrict__ x, const float4* __restrict__ scal,
    const int* __restrict__ edge, const ushort16* __restrict__ y1h,
    const ushort16* __restrict__ y2h, float* __restrict__ out) {
    __shared__ __align__(16) float lds[4][576];
    int wave = threadIdx.x >> 6;
    int t    = threadIdx.x & 63;
    int ent  = blockIdx.x * 4 + wave;

    int n = edge[ent];
    float4 sc = scal[n];                       // {1/d, rsqrt, sqrt, 0}
    float xv = x[n * D_FEAT + t];
    size_t nb = (size_t)n * 64 + t;

    float h[9];
    h[0] = xv;                      h[1] = xv * sc.y;                h[2] = xv * sc.z;
    h[3] = bf1(y1h[nb]);            h[4] = bf1(y1h[nb + PLANE_US]);  h[5] = bf1(y1h[nb + 2*PLANE_US]);
    h[6] = bf1(y2h[nb]);            h[7] = bf1(y2h[nb + PLANE_US]);  h[8] = bf1(y2h[nb + 2*PLANE_US]);

#pragma unroll
    for (int g = 0; g < 9; ++g) lds[wave][t * 9 + g] = h[g];  // 2-way alias: free
    __syncthreads();

    const float4* l4 = (const float4*)lds[wave];
    float4* o4 = (float4*)(out + (size_t)ent * 576);   // 144 float4 per entry
    o4[t]      = l4[t];
    o4[t + 64] = l4[t + 64];
    if (t < 16) o4[t + 128] = l4[t + 128];
}

// ---------------------------------------------------------------------------
extern "C" void kernel_launch(void* const* d_in, const int* in_sizes, int n_in,
                              void* d_out, int out_size, void* d_ws, size_t ws_size,
                              hipStream_t stream) {
    const float* x       = (const float*)d_in[0];   // [N, 64]
    const float* deg     = (const float*)d_in[1];   // [N, 1]
    const int*   adj_row = (const int*)d_in[2];     // [nnz] sorted
    const int*   adj_col = (const int*)d_in[3];     // [nnz]
    const int*   edge    = (const int*)d_in[4];     // [2, 32768]
    float* out = (float*)d_out;

    // Workspace (rewritten fully every call)
    char* ws = (char*)d_ws;
    size_t off = 0;
    int*    row_ptr = (int*)ws;            off = ((size_t)(N_NODES + 1) * 4 + 255) & ~(size_t)255;
    float4* scal    = (float4*)(ws + off); off += (size_t)N_NODES * 16;
    uint32* xh      = (uint32*)(ws + off); off += (size_t)N_NODES * 64 * 2;
    off = (off + 255) & ~(size_t)255;
    uint4*  y1h     = (uint4*)(ws + off);  off += (size_t)N_NODES * 192 * 2;
    off = (off + 255) & ~(size_t)255;
    uint4*  y2h     = (uint4*)(ws + off);  off += (size_t)N_NODES * 192 * 2;
    off = (off + 255) & ~(size_t)255;
    int*    flag    = (int*)(ws + off);    off += (size_t)N_NODES * 4;
    int*    perm1   = (int*)(ws + off);    off += (size_t)N_NODES * 4;
    int*    perm2   = (int*)(ws + off);    off += (size_t)N_NODES * 4;
    off = (off + 255) & ~(size_t)255;
    int*    hist1   = (int*)(ws + off);    off += 64 * 4;
    int*    hist2   = (int*)(ws + off);    off += 64 * 4;
    int*    cur1    = (int*)(ws + off);    off += 64 * 4;
    int*    cur2    = (int*)(ws + off);    off += 64 * 4;
    int*    n_need  = (int*)(ws + off);    off += 4;

    int nrb = (N_NODES + 255) / 256;                // row-parallel blocks
    int nblk = (N_NODES + 31) / 32;                 // spmm blocks (worst case)

    build_rowptr_scal<<<(N_NODES + 1 + 255) / 256, 256, 0, stream>>>(
        adj_row, deg, row_ptr, scal, flag, hist1, hist2, N_NNZ, N_NODES);
    pack_x<<<(N_NODES * 32 + 255) / 256, 256, 0, stream>>>(
        (const float2*)x, xh, edge, flag, N_NODES * 32);
    hist_kernel<<<nrb, 256, 0, stream>>>(row_ptr, flag, hist1, hist2, N_NODES);
    prefix_kernel<<<1, 64, 0, stream>>>(hist1, hist2, cur1, cur2, n_need);
    scatter_kernel<<<nrb, 256, 0, stream>>>(row_ptr, flag, cur1, cur2,
                                            perm1, perm2, N_NODES);
    spmm1_kernel<<<nblk, 256, 0, stream>>>(
        (const uint4*)xh, scal, adj_col, row_ptr, perm1, y1h, N_NODES);
    spmm2_kernel<<<dim3(nblk, 3), 256, 0, stream>>>(
        (const float4*)x, scal, adj_col, row_ptr, perm2, n_need, y1h, y2h);
    gather_kernel<<<N_ENT / 4, 256, 0, stream>>>(
        x, scal, edge, (const ushort16*)y1h, (const ushort16*)y2h, out);
}

// Round 6
// 256.646 us; speedup vs baseline: 2.3221x; 2.3221x over previous
//
#include <hip/hip_runtime.h>

#define N_NODES 50000
#define D_FEAT 64
#define N_NNZ 800000
#define N_ENT 65536   // 2 * 32768 edge endpoints

typedef unsigned int uint32;
typedef unsigned short ushort16;

// Plane strides for plane-major [3][N][64] bf16 tables
#define PLANE_U4 ((size_t)N_NODES * 8)    // in uint4 (16B) units
#define PLANE_US ((size_t)N_NODES * 64)   // in ushort units

// ---- bf16 helpers ---------------------------------------------------------
__device__ __forceinline__ uint32 rne1(float a) {
    uint32 u = __float_as_uint(a);
    return (u + 0x7FFFu + ((u >> 16) & 1u)) >> 16;
}
__device__ __forceinline__ uint32 rne2(float a, float b) {   // pack [a:lo, b:hi]
    return rne1(a) | (rne1(b) << 16);
}
__device__ __forceinline__ float bf_lo(uint32 u) { return __uint_as_float(u << 16); }
__device__ __forceinline__ float bf_hi(uint32 u) { return __uint_as_float(u & 0xFFFF0000u); }
__device__ __forceinline__ void unpack8(const uint4 v, float* f) {
    f[0] = bf_lo(v.x); f[1] = bf_hi(v.x);
    f[2] = bf_lo(v.y); f[3] = bf_hi(v.y);
    f[4] = bf_lo(v.z); f[5] = bf_hi(v.z);
    f[6] = bf_lo(v.w); f[7] = bf_hi(v.w);
}
__device__ __forceinline__ float bf1(ushort16 u) { return __uint_as_float(((uint32)u) << 16); }

// ---------------------------------------------------------------------------
// 1a) CSR row pointers (binary search over sorted adj_row) + per-node scalars
//     scal[n] = {1/deg, rsqrt(deg), sqrt(deg), 0}. Also zeros flag[] and
//     the two degree histograms (used by later dispatches on this stream).
// ---------------------------------------------------------------------------
__global__ void build_rowptr_scal(const int* __restrict__ adj_row,
                                  const float* __restrict__ deg,
                                  int* __restrict__ row_ptr,
                                  float4* __restrict__ scal,
                                  int* __restrict__ flag,
                                  int* __restrict__ hist1,
                                  int* __restrict__ hist2,
                                  int nnz, int n) {
    int r = blockIdx.x * blockDim.x + threadIdx.x;
    if (r > n) return;
    int lo = 0, hi = nnz;           // first idx with adj_row[idx] >= r
    while (lo < hi) {
        int mid = (lo + hi) >> 1;
        if (adj_row[mid] < r) lo = mid + 1; else hi = mid;
    }
    row_ptr[r] = lo;
    if (r < n) {
        float d  = deg[r];
        float sq = sqrtf(d);
        scal[r] = make_float4(1.0f / d, 1.0f / sq, sq, 0.0f);
        flag[r] = 0;
    }
    if (r < 64) { hist1[r] = 0; hist2[r] = 0; }
}

// 1b) x (fp32) -> xh (bf16 pairs); also flags edge-endpoint nodes.
__global__ __launch_bounds__(256) void pack_x(const float2* __restrict__ x2,
                                              uint32* __restrict__ xh,
                                              const int* __restrict__ edge,
                                              int* __restrict__ flag, int npair) {
    int i = blockIdx.x * blockDim.x + threadIdx.x;
    if (i >= npair) return;
    float2 v = x2[i];
    xh[i] = rne2(v.x, v.y);
    if (i < N_ENT) flag[edge[i]] = 1;        // benign write race
}

// 1c) degree histogram, LDS-aggregated: block-local 64-bin histogram in LDS,
//     then <=64 non-returning global atomics per block (no per-thread global
//     atomics -- round-3's scatter burned 203us on 50k fetch-adds to 64 addrs).
__global__ __launch_bounds__(256) void hist_kernel(
    const int* __restrict__ row_ptr, const int* __restrict__ flag,
    int* __restrict__ hist1, int* __restrict__ hist2, int n) {
    __shared__ int lh1[64], lh2[64];
    int t = threadIdx.x;
    if (t < 64) { lh1[t] = 0; lh2[t] = 0; }
    __syncthreads();
    int r = blockIdx.x * blockDim.x + t;
    if (r < n) {
        int b = min(row_ptr[r + 1] - row_ptr[r], 63);
        atomicAdd(&lh1[b], 1);
        if (flag[r]) atomicAdd(&lh2[b], 1);
    }
    __syncthreads();
    if (t < 64) {
        if (lh1[t]) atomicAdd(&hist1[t], lh1[t]);
        if (lh2[t]) atomicAdd(&hist2[t], lh2[t]);
    }
}

// 1d) descending-degree exclusive prefix -> bucket cursors; n_needed count.
__global__ void prefix_kernel(const int* __restrict__ hist1,
                              const int* __restrict__ hist2,
                              int* __restrict__ cur1, int* __restrict__ cur2,
                              int* __restrict__ n_needed) {
    if (threadIdx.x == 0) {
        int acc = 0;
        for (int b = 63; b >= 0; --b) { cur1[b] = acc; acc += hist1[b]; }
        int acc2 = 0;
        for (int b = 63; b >= 0; --b) { cur2[b] = acc2; acc2 += hist2[b]; }
        *n_needed = acc2;
    }
}

// 1e) scatter rows into degree-sorted perms. Two-level rank: per-thread rank
//     from LDS fetch-add (block-local), per-block bucket base from ONE global
//     fetch-add per bucket per block. Within-bucket order is arbitrary --
//     irrelevant for correctness (equal-degree grouping is all that matters).
__global__ __launch_bounds__(256) void scatter_kernel(
    const int* __restrict__ row_ptr, const int* __restrict__ flag,
    int* __restrict__ cur1, int* __restrict__ cur2,
    int* __restrict__ perm1, int* __restrict__ perm2, int n) {
    __shared__ int lh1[64], lh2[64], lb1[64], lb2[64];
    int t = threadIdx.x;
    if (t < 64) { lh1[t] = 0; lh2[t] = 0; }
    __syncthreads();
    int r = blockIdx.x * blockDim.x + t;
    int b = 0, rk1 = 0, rk2 = 0, fl = 0;
    if (r < n) {
        b = min(row_ptr[r + 1] - row_ptr[r], 63);
        rk1 = atomicAdd(&lh1[b], 1);
        fl = flag[r];
        if (fl) rk2 = atomicAdd(&lh2[b], 1);
    }
    __syncthreads();
    if (t < 64) {
        if (lh1[t]) lb1[t] = atomicAdd(&cur1[t], lh1[t]);
        if (lh2[t]) lb2[t] = atomicAdd(&cur2[t], lh2[t]);
    }
    __syncthreads();
    if (r < n) {
        perm1[lb1[b] + rk1] = r;
        if (fl) perm2[lb2[b] + rk2] = r;
    }
}

// ---------------------------------------------------------------------------
// 2) y1 = degrev * spmm(x3). Wave = 8 rows via perm1 (equal degree), octet
//    walks its row serially (2-way MLP). Output plane-major [3][N][64] bf16.
// ---------------------------------------------------------------------------
__global__ __launch_bounds__(256) void spmm1_kernel(
    const uint4* __restrict__ xh, const float4* __restrict__ scal,
    const int* __restrict__ adj_col, const int* __restrict__ row_ptr,
    const int* __restrict__ perm1,
    uint4* __restrict__ y1h, int n) {
    int t    = threadIdx.x & 63;
    int f    = t & 7;                                  // feature block
    int idx  = (blockIdx.x * 4 + (threadIdx.x >> 6)) * 8 + (t >> 3);
    if (idx >= n) return;
    int r = perm1[idx];

    int s = row_ptr[r], e = row_ptr[r + 1];
    int cnt = e - s;
    float a0[8], a1[8], a2[8];
#pragma unroll
    for (int j = 0; j < 8; ++j) { a0[j] = 0.f; a1[j] = 0.f; a2[j] = 0.f; }

    int i = 0;
    for (; i + 2 <= cnt; i += 2) {
        int c0 = adj_col[s + i];
        int c1 = adj_col[s + i + 1];
        uint4 xv0 = xh[(size_t)c0 * 8 + f];
        uint4 xv1 = xh[(size_t)c1 * 8 + f];
        float4 sc0 = scal[c0];
        float4 sc1 = scal[c1];
        float xf0[8], xf1[8];
        unpack8(xv0, xf0); unpack8(xv1, xf1);
#pragma unroll
        for (int j = 0; j < 8; ++j) {
            a0[j] += xf0[j];
            a1[j] += xf0[j] * sc0.y;
            a2[j] += xf0[j] * sc0.z;
            a0[j] += xf1[j];
            a1[j] += xf1[j] * sc1.y;
            a2[j] += xf1[j] * sc1.z;
        }
    }
    if (i < cnt) {
        int c = adj_col[s + i];
        uint4 xv = xh[(size_t)c * 8 + f];
        float4 sc = scal[c];
        float xf[8]; unpack8(xv, xf);
#pragma unroll
        for (int j = 0; j < 8; ++j) {
            a0[j] += xf[j];
            a1[j] += xf[j] * sc.y;
            a2[j] += xf[j] * sc.z;
        }
    }

    float dr = scal[r].x;
    size_t base = (size_t)r * 8 + f;
    y1h[base]               = make_uint4(rne2(a0[0]*dr, a0[1]*dr), rne2(a0[2]*dr, a0[3]*dr),
                                         rne2(a0[4]*dr, a0[5]*dr), rne2(a0[6]*dr, a0[7]*dr));
    y1h[base + PLANE_U4]    = make_uint4(rne2(a1[0]*dr, a1[1]*dr), rne2(a1[2]*dr, a1[3]*dr),
                                         rne2(a1[4]*dr, a1[5]*dr), rne2(a1[6]*dr, a1[7]*dr));
    y1h[base + 2*PLANE_U4]  = make_uint4(rne2(a2[0]*dr, a2[1]*dr), rne2(a2[2]*dr, a2[3]*dr),
                                         rne2(a2[4]*dr, a2[5]*dr), rne2(a2[6]*dr, a2[7]*dr));
}

// ---------------------------------------------------------------------------
// 3) y2 = degrev * spmm(y1) - x3, one group per pass (blockIdx.y), rows via
//    perm2 (edge-needed only, ~73% of N, equal-degree waves). Surplus blocks
//    early-exit on device-side count (no host sync).
// ---------------------------------------------------------------------------
__global__ __launch_bounds__(256) void spmm2_kernel(
    const float4* __restrict__ x4, const float4* __restrict__ scal,
    const int* __restrict__ adj_col, const int* __restrict__ row_ptr,
    const int* __restrict__ perm2, const int* __restrict__ n_needed,
    const uint4* __restrict__ y1h, uint4* __restrict__ y2h) {
    int t = threadIdx.x & 63;
    int f = t & 7;
    int idx = (blockIdx.x * 4 + (threadIdx.x >> 6)) * 8 + (t >> 3);
    int g = blockIdx.y;
    if (idx >= *n_needed) return;
    int r = perm2[idx];
    const uint4* yp = y1h + (size_t)g * PLANE_U4;

    int s = row_ptr[r], e = row_ptr[r + 1];
    int cnt = e - s;
    float a[8];
#pragma unroll
    for (int j = 0; j < 8; ++j) a[j] = 0.f;

    int i = 0;
    for (; i + 4 <= cnt; i += 4) {                 // 4 gathers in flight/octet
        int c0 = adj_col[s + i];
        int c1 = adj_col[s + i + 1];
        int c2 = adj_col[s + i + 2];
        int c3 = adj_col[s + i + 3];
        uint4 b0 = yp[(size_t)c0 * 8 + f];
        uint4 b1 = yp[(size_t)c1 * 8 + f];
        uint4 b2 = yp[(size_t)c2 * 8 + f];
        uint4 b3 = yp[(size_t)c3 * 8 + f];
        float f0[8], f1[8], f2[8], f3[8];
        unpack8(b0, f0); unpack8(b1, f1); unpack8(b2, f2); unpack8(b3, f3);
#pragma unroll
        for (int j = 0; j < 8; ++j)
            a[j] += (f0[j] + f1[j]) + (f2[j] + f3[j]);
    }
    for (; i < cnt; ++i) {
        int c = adj_col[s + i];
        uint4 b = yp[(size_t)c * 8 + f];
        float fv[8]; unpack8(b, fv);
#pragma unroll
        for (int j = 0; j < 8; ++j) a[j] += fv[j];
    }

    float4 sc = scal[r];                       // {1/d, rsqrt, sqrt, 0}
    float w = (g == 0) ? 1.0f : ((g == 1) ? sc.y : sc.z);
    float4 xa = x4[(size_t)r * 16 + f * 2];
    float4 xb = x4[(size_t)r * 16 + f * 2 + 1];
    float xr[8] = {xa.x, xa.y, xa.z, xa.w, xb.x, xb.y, xb.z, xb.w};
    float v[8];
#pragma unroll
    for (int j = 0; j < 8; ++j) v[j] = sc.x * a[j] - xr[j] * w;

    uint4* yr = y2h + (size_t)g * PLANE_U4 + (size_t)r * 8 + f;
    yr[0] = make_uint4(rne2(v[0], v[1]), rne2(v[2], v[3]),
                       rne2(v[4], v[5]), rne2(v[6], v[7]));
}

// ---------------------------------------------------------------------------
// 4) Output gather + [64,9] transpose through LDS; float4 store path.
//    out[ent, d, g]: g 0..2 = x*{1,rsqrt,sqrt}, g 3..5 = y1, g 6..8 = y2.
//    y1/y2 plane-major: plane stride N*64 ushorts.
// ---------------------------------------------------------------------------
__global__ __launch_bounds__(256) void gather_kernel(
    const float* __restrict__ x, const float4* __restrict__ scal,
    const int* __restrict__ edge, const ushort16* __restrict__ y1h,
    const ushort16* __restrict__ y2h, float* __restrict__ out) {
    __shared__ __align__(16) float lds[4][576];
    int wave = threadIdx.x >> 6;
    int t    = threadIdx.x & 63;
    int ent  = blockIdx.x * 4 + wave;

    int n = edge[ent];
    float4 sc = scal[n];                       // {1/d, rsqrt, sqrt, 0}
    float xv = x[n * D_FEAT + t];
    size_t nb = (size_t)n * 64 + t;

    float h[9];
    h[0] = xv;                      h[1] = xv * sc.y;                h[2] = xv * sc.z;
    h[3] = bf1(y1h[nb]);            h[4] = bf1(y1h[nb + PLANE_US]);  h[5] = bf1(y1h[nb + 2*PLANE_US]);
    h[6] = bf1(y2h[nb]);            h[7] = bf1(y2h[nb + PLANE_US]);  h[8] = bf1(y2h[nb + 2*PLANE_US]);

#pragma unroll
    for (int g = 0; g < 9; ++g) lds[wave][t * 9 + g] = h[g];  // 2-way alias: free
    __syncthreads();

    const float4* l4 = (const float4*)lds[wave];
    float4* o4 = (float4*)(out + (size_t)ent * 576);   // 144 float4 per entry
    o4[t]      = l4[t];
    o4[t + 64] = l4[t + 64];
    if (t < 16) o4[t + 128] = l4[t + 128];
}

// ---------------------------------------------------------------------------
extern "C" void kernel_launch(void* const* d_in, const int* in_sizes, int n_in,
                              void* d_out, int out_size, void* d_ws, size_t ws_size,
                              hipStream_t stream) {
    const float* x       = (const float*)d_in[0];   // [N, 64]
    const float* deg     = (const float*)d_in[1];   // [N, 1]
    const int*   adj_row = (const int*)d_in[2];     // [nnz] sorted
    const int*   adj_col = (const int*)d_in[3];     // [nnz]
    const int*   edge    = (const int*)d_in[4];     // [2, 32768]
    float* out = (float*)d_out;

    // Workspace (rewritten fully every call)
    char* ws = (char*)d_ws;
    size_t off = 0;
    int*    row_ptr = (int*)ws;            off = ((size_t)(N_NODES + 1) * 4 + 255) & ~(size_t)255;
    float4* scal    = (float4*)(ws + off); off += (size_t)N_NODES * 16;
    uint32* xh      = (uint32*)(ws + off); off += (size_t)N_NODES * 64 * 2;
    off = (off + 255) & ~(size_t)255;
    uint4*  y1h     = (uint4*)(ws + off);  off += (size_t)N_NODES * 192 * 2;
    off = (off + 255) & ~(size_t)255;
    uint4*  y2h     = (uint4*)(ws + off);  off += (size_t)N_NODES * 192 * 2;
    off = (off + 255) & ~(size_t)255;
    int*    flag    = (int*)(ws + off);    off += (size_t)N_NODES * 4;
    int*    perm1   = (int*)(ws + off);    off += (size_t)N_NODES * 4;
    int*    perm2   = (int*)(ws + off);    off += (size_t)N_NODES * 4;
    off = (off + 255) & ~(size_t)255;
    int*    hist1   = (int*)(ws + off);    off += 64 * 4;
    int*    hist2   = (int*)(ws + off);    off += 64 * 4;
    int*    cur1    = (int*)(ws + off);    off += 64 * 4;
    int*    cur2    = (int*)(ws + off);    off += 64 * 4;
    int*    n_need  = (int*)(ws + off);    off += 4;

    int nrb = (N_NODES + 255) / 256;                // row-parallel blocks
    int nblk = (N_NODES + 31) / 32;                 // spmm blocks (worst case)

    build_rowptr_scal<<<(N_NODES + 1 + 255) / 256, 256, 0, stream>>>(
        adj_row, deg, row_ptr, scal, flag, hist1, hist2, N_NNZ, N_NODES);
    pack_x<<<(N_NODES * 32 + 255) / 256, 256, 0, stream>>>(
        (const float2*)x, xh, edge, flag, N_NODES * 32);
    hist_kernel<<<nrb, 256, 0, stream>>>(row_ptr, flag, hist1, hist2, N_NODES);
    prefix_kernel<<<1, 64, 0, stream>>>(hist1, hist2, cur1, cur2, n_need);
    scatter_kernel<<<nrb, 256, 0, stream>>>(row_ptr, flag, cur1, cur2,
                                            perm1, perm2, N_NODES);
    spmm1_kernel<<<nblk, 256, 0, stream>>>(
        (const uint4*)xh, scal, adj_col, row_ptr, perm1, y1h, N_NODES);
    spmm2_kernel<<<dim3(nblk, 3), 256, 0, stream>>>(
        (const float4*)x, scal, adj_col, row_ptr, perm2, n_need, y1h, y2h);
    gather_kernel<<<N_ENT / 4, 256, 0, stream>>>(
        x, scal, edge, (const ushort16*)y1h, (const ushort16*)y2h, out);
}